// Round 7
// baseline (654.795 us; speedup 1.0000x reference)
//
#include <hip/hip_runtime.h>
#include <hip/hip_bf16.h>

#define H_DIM 2048
#define I_DIM 768
#define NEXP 64
#define TOPK 8
#define NTOK 1024   // B*S
#define BMT 192     // token tile: count ~128+-11, max ~165 => single chunk
#define BKS 32      // K per step

typedef float f32x4 __attribute__((ext_vector_type(4)));
typedef short bf16v8 __attribute__((ext_vector_type(8)));   // 8 bf16 in 4 VGPRs
typedef unsigned int u32;

// ---------------- workspace layout (bytes) ----------------
// topk_idx : int   [NTOK*TOPK]           @ 0
// topk_w   : float [NTOK*TOPK]           @ 32768
// counts   : int   [NEXP]                @ 65536
// offsets  : int   [NEXP]                @ 65792
// lists    : int   [NEXP*NTOK]           @ 66048
// wlist    : float [NEXP*NTOK]           @ 328192
// hmid     : bf16  [NTOK*TOPK * I_DIM]   @ 590336   (12.58 MB)
// xbf      : bf16  [NTOK * H_DIM]        @ 13173248 (4 MB)

__device__ inline unsigned short f2bf(float f) {
    union { float f; u32 u; } v; v.f = f;
    u32 r = (v.u + 0x7FFFu + ((v.u >> 16) & 1u)) >> 16;
    return (unsigned short)r;
}
__device__ inline u32 pack2(float a, float b) {
    return (u32)f2bf(a) | ((u32)f2bf(b) << 16);
}

__global__ void zero_kernel(float4* p, int n4) {
    int i = blockIdx.x * blockDim.x + threadIdx.x;
    if (i < n4) p[i] = (float4){0.f, 0.f, 0.f, 0.f};
}

__global__ void xconv_kernel(const float4* __restrict__ x, ushort4* __restrict__ xbf, int n4) {
    int i = blockIdx.x * blockDim.x + threadIdx.x;
    if (i < n4) {
        float4 v = x[i];
        ushort4 o;
        o.x = f2bf(v.x); o.y = f2bf(v.y); o.z = f2bf(v.z); o.w = f2bf(v.w);
        xbf[i] = o;
    }
}

// one block per token, 64 threads (one per expert) -- verified R1-R6
__global__ __launch_bounds__(64) void router_kernel(
    const float* __restrict__ x, const float* __restrict__ Wr,
    int* __restrict__ topk_idx, float* __restrict__ topk_w)
{
    const int t = blockIdx.x;
    const int e = threadIdx.x;
    __shared__ float xs[H_DIM];

    const float* xrow = x + (size_t)t * H_DIM;
    #pragma unroll
    for (int m = 0; m < H_DIM / 64; ++m) xs[m * 64 + e] = xrow[m * 64 + e];
    __syncthreads();

    float acc = 0.f;
    #pragma unroll 8
    for (int h = 0; h < H_DIM; ++h) acc += xs[h] * Wr[(size_t)h * NEXP + e];

    float m = acc;
    #pragma unroll
    for (int o = 32; o > 0; o >>= 1) m = fmaxf(m, __shfl_xor(m, o));
    float p = __expf(acc - m);
    float s = p;
    #pragma unroll
    for (int o = 32; o > 0; o >>= 1) s += __shfl_xor(s, o);
    float prob = p / s;

    float myp = prob;
    float kw[TOPK]; int kid[TOPK]; float wsum = 0.f;
    #pragma unroll
    for (int k = 0; k < TOPK; ++k) {
        float v = myp; int bi = e;
        #pragma unroll
        for (int o = 32; o > 0; o >>= 1) {
            float ov = __shfl_xor(v, o);
            int   oi = __shfl_xor(bi, o);
            if (ov > v || (ov == v && oi < bi)) { v = ov; bi = oi; }
        }
        kw[k] = v; kid[k] = bi; wsum += v;
        if (e == bi) myp = -1.f;
    }
    if (e == 0) {
        float inv = 1.f / wsum;
        #pragma unroll
        for (int k = 0; k < TOPK; ++k) {
            topk_idx[t * TOPK + k] = kid[k];
            topk_w[t * TOPK + k]   = kw[k] * inv;
        }
    }
}

__global__ __launch_bounds__(64) void listbuild_kernel(
    const int* __restrict__ topk_idx, const float* __restrict__ topk_w,
    int* __restrict__ counts, int* __restrict__ lists, float* __restrict__ wlist)
{
    const int e = blockIdx.x;
    const int lane = threadIdx.x;
    int n = 0;
    for (int base = 0; base < NTOK * TOPK; base += 64) {
        int s = base + lane;
        int idx = topk_idx[s];
        bool match = (idx == e);
        unsigned long long mask = __ballot(match);
        int pre = __popcll(mask & ((1ull << lane) - 1ull));
        if (match) {
            lists[e * NTOK + n + pre] = s >> 3;
            wlist[e * NTOK + n + pre] = topk_w[s];
        }
        n += __popcll(mask);
    }
    if (lane == 0) counts[e] = n;
}

__global__ __launch_bounds__(64) void scan_kernel(
    const int* __restrict__ counts, int* __restrict__ offsets)
{
    int e = threadIdx.x;
    int v = counts[e];
    int xacc = v;
    #pragma unroll
    for (int o = 1; o < 64; o <<= 1) {
        int y = __shfl_up(xacc, o);
        if (e >= o) xacc += y;
    }
    offsets[e] = xacc - v;
}

#define MFMA_BF16 __builtin_amdgcn_mfma_f32_16x16x32_bf16

// ---------------- gate+up: grid 1536 (xcd-swizzled), block 384 ----------------
// A (x rows) direct global->reg fragments; B (weights) reg->LDS dbuf, pad-20
__global__ __launch_bounds__(384) void gateup_kernel(
    const unsigned short* __restrict__ xbf,
    const float* __restrict__ Wg, const float* __restrict__ Wu,
    const int* __restrict__ counts, const int* __restrict__ offsets,
    const int* __restrict__ lists, const float* __restrict__ wlist,
    unsigned short* __restrict__ hmid)
{
    const int b  = blockIdx.x;
    const int wg = (b & 7) * 192 + (b >> 3);     // bijective: 1536 = 8*192
    const int itile = wg % 24;                   // 24 itiles of 32 cols
    const int e     = wg / 24;

    const int count = counts[e];
    if (count == 0) return;
    const int off = offsets[e];
    const int i0 = itile * 32;

    __shared__ u32 Blds[2][2][32 * 20];          // [buf][mat][n*20 + kpair], 10240 B

    const int tid  = threadIdx.x;
    const int lane = tid & 63;
    const int wid  = tid >> 6;                   // 0..5 (M position, 32 rows each)
    const int kb   = lane >> 4;                  // 0..3
    const int l15  = lane & 15;

    // B staging: 256 threads, thread -> (mat, k-pair, col-quad)
    const bool bstage = tid < 256;
    const int  bmat   = (tid >> 7) & 1;
    const int  bidx   = tid & 127;
    const int  bkp    = bidx >> 3;               // 0..15 (rows 2bkp, 2bkp+1)
    const int  bn4    = (bidx & 7) * 4;          // 0..28
    const float* WB = (bmat ? Wu : Wg) + (size_t)e * H_DIM * I_DIM + i0 + bn4;

    for (int mstart = 0; mstart < count; mstart += BMT) {
        const bool mact = (mstart + wid * 32) < count;

        // per-lane A row base pointers (clamped)
        const unsigned short* aptr0;
        const unsigned short* aptr1;
        {
            int r0 = mstart + wid * 32 + l15;
            int r1 = r0 + 16;
            int p0 = r0 < count ? r0 : count - 1;
            int p1 = r1 < count ? r1 : count - 1;
            aptr0 = xbf + (size_t)lists[e * NTOK + p0] * H_DIM + kb * 8;
            aptr1 = xbf + (size_t)lists[e * NTOK + p1] * H_DIM + kb * 8;
        }

        f32x4 accg[2][2], accu[2][2];
        #pragma unroll
        for (int i = 0; i < 2; ++i)
            #pragma unroll
            for (int j = 0; j < 2; ++j) {
                accg[i][j] = (f32x4){0.f, 0.f, 0.f, 0.f};
                accu[i][j] = (f32x4){0.f, 0.f, 0.f, 0.f};
            }

        f32x4 rB0, rB1;
        bf16v8 afA0, afA1, afB0, afB1;

#define GU_LOADB(h)                                                             \
        if (bstage) {                                                           \
            rB0 = __builtin_nontemporal_load((const f32x4*)(WB + (size_t)((h) + 2 * bkp)     * I_DIM)); \
            rB1 = __builtin_nontemporal_load((const f32x4*)(WB + (size_t)((h) + 2 * bkp + 1) * I_DIM)); \
        }
#define GU_STOREB(bufi)                                                         \
        if (bstage) {                                                           \
            u32* d_ = &Blds[bufi][bmat][0];                                     \
            d_[(bn4 + 0) * 20 + bkp] = pack2(rB0.x, rB1.x);                     \
            d_[(bn4 + 1) * 20 + bkp] = pack2(rB0.y, rB1.y);                     \
            d_[(bn4 + 2) * 20 + bkp] = pack2(rB0.z, rB1.z);                     \
            d_[(bn4 + 3) * 20 + bkp] = pack2(rB0.w, rB1.w);                     \
        }
#define GU_LOADA(A0, A1, h)                                                     \
        if (mact) {                                                             \
            A0 = *(const bf16v8*)(aptr0 + (h));                                 \
            A1 = *(const bf16v8*)(aptr1 + (h));                                 \
        }
#define GU_MFMA(bufi, A0, A1)                                                   \
        if (mact) {                                                             \
            bf16v8 bg0 = *(const bf16v8*)&Blds[bufi][0][(l15     ) * 20 + kb * 4]; \
            bf16v8 bg1 = *(const bf16v8*)&Blds[bufi][0][(l15 + 16) * 20 + kb * 4]; \
            bf16v8 bu0 = *(const bf16v8*)&Blds[bufi][1][(l15     ) * 20 + kb * 4]; \
            bf16v8 bu1 = *(const bf16v8*)&Blds[bufi][1][(l15 + 16) * 20 + kb * 4]; \
            accg[0][0] = MFMA_BF16(A0, bg0, accg[0][0], 0, 0, 0);               \
            accg[0][1] = MFMA_BF16(A0, bg1, accg[0][1], 0, 0, 0);               \
            accg[1][0] = MFMA_BF16(A1, bg0, accg[1][0], 0, 0, 0);               \
            accg[1][1] = MFMA_BF16(A1, bg1, accg[1][1], 0, 0, 0);               \
            accu[0][0] = MFMA_BF16(A0, bu0, accu[0][0], 0, 0, 0);               \
            accu[0][1] = MFMA_BF16(A0, bu1, accu[0][1], 0, 0, 0);               \
            accu[1][0] = MFMA_BF16(A1, bu0, accu[1][0], 0, 0, 0);               \
            accu[1][1] = MFMA_BF16(A1, bu1, accu[1][1], 0, 0, 0);               \
        }

        GU_LOADB(0); GU_LOADA(afA0, afA1, 0);
        GU_STOREB(0);
        __syncthreads();
        GU_LOADB(BKS); GU_LOADA(afB0, afB1, BKS);

        for (int t = 0; t < 64; t += 2) {
            GU_MFMA(0, afA0, afA1);
            __syncthreads();
            GU_STOREB(1);                         // B(t+1)
            __syncthreads();
            if (t + 2 < 64) { GU_LOADB((t + 2) * BKS); GU_LOADA(afA0, afA1, (t + 2) * BKS); }

            GU_MFMA(1, afB0, afB1);
            __syncthreads();
            if (t + 2 < 64) { GU_STOREB(0); }     // B(t+2)
            __syncthreads();
            if (t + 3 < 64) { GU_LOADB((t + 3) * BKS); GU_LOADA(afB0, afB1, (t + 3) * BKS); }
        }
#undef GU_LOADB
#undef GU_STOREB
#undef GU_LOADA
#undef GU_MFMA

        // epilogue: silu(g)*u*w -> hmid (bf16)
        if (mact) {
            #pragma unroll
            for (int mf = 0; mf < 2; ++mf)
                #pragma unroll
                for (int nf = 0; nf < 2; ++nf)
                    #pragma unroll
                    for (int r = 0; r < 4; ++r) {
                        int pos = mstart + wid * 32 + mf * 16 + kb * 4 + r;
                        if (pos < count) {
                            float wgt = wlist[e * NTOK + pos];
                            float g = (mf ? accg[1][nf] : accg[0][nf])[r];
                            float u = (mf ? accu[1][nf] : accu[0][nf])[r];
                            float s = 1.f / (1.f + __expf(-g));
                            hmid[(size_t)(off + pos) * I_DIM + i0 + nf * 16 + l15] = f2bf(g * s * u * wgt);
                        }
                    }
        }
    }
}

// ---------------- down: grid 4096 (xcd-swizzled), block 384 ----------------
__global__ __launch_bounds__(384) void down_kernel(
    const unsigned short* __restrict__ hmid, const float* __restrict__ Wd,
    const int* __restrict__ counts, const int* __restrict__ offsets,
    const int* __restrict__ lists, float* __restrict__ out)
{
    const int b  = blockIdx.x;
    const int wg = (b & 7) * 512 + (b >> 3);     // bijective: 4096 = 8*512
    const int htile = wg % 64;                   // 64 htiles of 32 cols
    const int e     = wg / 64;

    const int count = counts[e];
    if (count == 0) return;
    const int off = offsets[e];
    const int h0 = htile * 32;

    __shared__ u32 Blds[2][32 * 20];             // 5120 B

    const int tid  = threadIdx.x;
    const int lane = tid & 63;
    const int wid  = tid >> 6;
    const int kb   = lane >> 4;
    const int l15  = lane & 15;

    const bool bstage = tid < 128;
    const int  bkp    = (tid >> 3) & 15;
    const int  bn4    = (tid & 7) * 4;
    const float* WB = Wd + (size_t)e * I_DIM * H_DIM + h0 + bn4;

    for (int mstart = 0; mstart < count; mstart += BMT) {
        const bool mact = (mstart + wid * 32) < count;

        const unsigned short* aptr0;
        const unsigned short* aptr1;
        {
            int r0 = mstart + wid * 32 + l15;
            int r1 = r0 + 16;
            int p0 = r0 < count ? r0 : count - 1;
            int p1 = r1 < count ? r1 : count - 1;
            aptr0 = hmid + (size_t)(off + p0) * I_DIM + kb * 8;
            aptr1 = hmid + (size_t)(off + p1) * I_DIM + kb * 8;
        }

        f32x4 acc[2][2];
        #pragma unroll
        for (int i = 0; i < 2; ++i)
            #pragma unroll
            for (int j = 0; j < 2; ++j) acc[i][j] = (f32x4){0.f, 0.f, 0.f, 0.f};

        f32x4 rB0, rB1;
        bf16v8 afA0, afA1, afB0, afB1;

#define DN_LOADB(h)                                                             \
        if (bstage) {                                                           \
            rB0 = __builtin_nontemporal_load((const f32x4*)(WB + (size_t)((h) + 2 * bkp)     * H_DIM)); \
            rB1 = __builtin_nontemporal_load((const f32x4*)(WB + (size_t)((h) + 2 * bkp + 1) * H_DIM)); \
        }
#define DN_STOREB(bufi)                                                         \
        if (bstage) {                                                           \
            u32* d_ = &Blds[bufi][0];                                           \
            d_[(bn4 + 0) * 20 + bkp] = pack2(rB0.x, rB1.x);                     \
            d_[(bn4 + 1) * 20 + bkp] = pack2(rB0.y, rB1.y);                     \
            d_[(bn4 + 2) * 20 + bkp] = pack2(rB0.z, rB1.z);                     \
            d_[(bn4 + 3) * 20 + bkp] = pack2(rB0.w, rB1.w);                     \
        }
#define DN_LOADA(A0, A1, h)                                                     \
        if (mact) {                                                             \
            A0 = *(const bf16v8*)(aptr0 + (h));                                 \
            A1 = *(const bf16v8*)(aptr1 + (h));                                 \
        }
#define DN_MFMA(bufi, A0, A1)                                                   \
        if (mact) {                                                             \
            bf16v8 bd0 = *(const bf16v8*)&Blds[bufi][(l15     ) * 20 + kb * 4]; \
            bf16v8 bd1 = *(const bf16v8*)&Blds[bufi][(l15 + 16) * 20 + kb * 4]; \
            acc[0][0] = MFMA_BF16(A0, bd0, acc[0][0], 0, 0, 0);                 \
            acc[0][1] = MFMA_BF16(A0, bd1, acc[0][1], 0, 0, 0);                 \
            acc[1][0] = MFMA_BF16(A1, bd0, acc[1][0], 0, 0, 0);                 \
            acc[1][1] = MFMA_BF16(A1, bd1, acc[1][1], 0, 0, 0);                 \
        }

        DN_LOADB(0); DN_LOADA(afA0, afA1, 0);
        DN_STOREB(0);
        __syncthreads();
        DN_LOADB(BKS); DN_LOADA(afB0, afB1, BKS);

        for (int t = 0; t < 24; t += 2) {
            DN_MFMA(0, afA0, afA1);
            __syncthreads();
            DN_STOREB(1);
            __syncthreads();
            if (t + 2 < 24) { DN_LOADB((t + 2) * BKS); DN_LOADA(afA0, afA1, (t + 2) * BKS); }

            DN_MFMA(1, afB0, afB1);
            __syncthreads();
            if (t + 2 < 24) { DN_STOREB(0); }
            __syncthreads();
            if (t + 3 < 24) { DN_LOADB((t + 3) * BKS); DN_LOADA(afB0, afB1, (t + 3) * BKS); }
        }
#undef DN_LOADB
#undef DN_STOREB
#undef DN_LOADA
#undef DN_MFMA

        if (mact) {
            #pragma unroll
            for (int mf = 0; mf < 2; ++mf)
                #pragma unroll
                for (int nf = 0; nf < 2; ++nf)
                    #pragma unroll
                    for (int r = 0; r < 4; ++r) {
                        int pos = mstart + wid * 32 + mf * 16 + kb * 4 + r;
                        if (pos < count) {
                            int tok = lists[e * NTOK + pos];
                            atomicAdd(&out[(size_t)tok * H_DIM + h0 + nf * 16 + l15],
                                      (mf ? acc[1][nf] : acc[0][nf])[r]);
                        }
                    }
        }
    }
}

extern "C" void kernel_launch(void* const* d_in, const int* in_sizes, int n_in,
                              void* d_out, int out_size, void* d_ws, size_t ws_size,
                              hipStream_t stream) {
    const float* x  = (const float*)d_in[0];
    const float* Wr = (const float*)d_in[1];
    const float* Wg = (const float*)d_in[2];
    const float* Wu = (const float*)d_in[3];
    const float* Wd = (const float*)d_in[4];
    float* out = (float*)d_out;

    char* ws = (char*)d_ws;
    int*   topk_idx = (int*)  (ws + 0);
    float* topk_w   = (float*)(ws + 32768);
    int*   counts   = (int*)  (ws + 65536);
    int*   offsets  = (int*)  (ws + 65792);
    int*   lists    = (int*)  (ws + 66048);
    float* wlist    = (float*)(ws + 328192);
    unsigned short* hmid = (unsigned short*)(ws + 590336);
    unsigned short* xbf  = (unsigned short*)(ws + 13173248);

    const int nout4 = NTOK * H_DIM / 4;
    hipLaunchKernelGGL(zero_kernel, dim3((nout4 + 255) / 256), dim3(256), 0, stream,
                       (float4*)out, nout4);
    hipLaunchKernelGGL(xconv_kernel, dim3((NTOK * H_DIM / 4 + 255) / 256), dim3(256), 0, stream,
                       (const float4*)x, (ushort4*)xbf, NTOK * H_DIM / 4);
    hipLaunchKernelGGL(router_kernel, dim3(NTOK), dim3(64), 0, stream,
                       x, Wr, topk_idx, topk_w);
    hipLaunchKernelGGL(listbuild_kernel, dim3(NEXP), dim3(64), 0, stream,
                       topk_idx, topk_w, counts, lists, wlist);
    hipLaunchKernelGGL(scan_kernel, dim3(1), dim3(64), 0, stream,
                       counts, offsets);
    hipLaunchKernelGGL(gateup_kernel, dim3(24 * NEXP), dim3(384), 0, stream,
                       xbf, Wg, Wu, counts, offsets, lists, wlist, hmid);
    hipLaunchKernelGGL(down_kernel, dim3(64 * NEXP), dim3(384), 0, stream,
                       hmid, Wd, counts, offsets, lists, out);
}

// Round 8
// 621.823 us; speedup vs baseline: 1.0530x; 1.0530x over previous
//
#include <hip/hip_runtime.h>
#include <hip/hip_bf16.h>

#define H_DIM 2048
#define I_DIM 768
#define NEXP 64
#define TOPK 8
#define NTOK 1024   // B*S
#define BMT 192     // token tile: count ~128+-11 (max ~165) => all waves live, single chunk
#define BKS 32      // K per step

typedef float f32x4 __attribute__((ext_vector_type(4)));
typedef unsigned int u32x4 __attribute__((ext_vector_type(4)));
typedef short bf16v8 __attribute__((ext_vector_type(8)));   // 8 bf16 in 4 VGPRs
typedef unsigned int u32;

#define NTLOAD __builtin_nontemporal_load

// ---------------- workspace layout (bytes) ----------------
// topk_idx : int   [NTOK*TOPK]           @ 0
// topk_w   : float [NTOK*TOPK]           @ 32768
// counts   : int   [NEXP]                @ 65536
// offsets  : int   [NEXP]                @ 65792
// lists    : int   [NEXP*NTOK]           @ 66048
// wlist    : float [NEXP*NTOK]           @ 328192
// hmid     : bf16  [NTOK*TOPK * I_DIM]   @ 590336   (12.58 MB)
// xbf      : bf16  [NTOK * H_DIM]        @ 13173248 (4 MB)

__device__ inline unsigned short f2bf(float f) {
    union { float f; u32 u; } v; v.f = f;
    u32 r = (v.u + 0x7FFFu + ((v.u >> 16) & 1u)) >> 16;
    return (unsigned short)r;
}
__device__ inline u32 pack2(float a, float b) {
    return (u32)f2bf(a) | ((u32)f2bf(b) << 16);
}

__global__ void zero_kernel(float4* p, int n4) {
    int i = blockIdx.x * blockDim.x + threadIdx.x;
    if (i < n4) p[i] = (float4){0.f, 0.f, 0.f, 0.f};
}

__global__ void xconv_kernel(const float4* __restrict__ x, ushort4* __restrict__ xbf, int n4) {
    int i = blockIdx.x * blockDim.x + threadIdx.x;
    if (i < n4) {
        float4 v = x[i];
        ushort4 o;
        o.x = f2bf(v.x); o.y = f2bf(v.y); o.z = f2bf(v.z); o.w = f2bf(v.w);
        xbf[i] = o;
    }
}

// one block per token, 64 threads (one per expert) -- verified R1-R7
__global__ __launch_bounds__(64) void router_kernel(
    const float* __restrict__ x, const float* __restrict__ Wr,
    int* __restrict__ topk_idx, float* __restrict__ topk_w)
{
    const int t = blockIdx.x;
    const int e = threadIdx.x;
    __shared__ float xs[H_DIM];

    const float* xrow = x + (size_t)t * H_DIM;
    #pragma unroll
    for (int m = 0; m < H_DIM / 64; ++m) xs[m * 64 + e] = xrow[m * 64 + e];
    __syncthreads();

    float acc = 0.f;
    #pragma unroll 8
    for (int h = 0; h < H_DIM; ++h) acc += xs[h] * Wr[(size_t)h * NEXP + e];

    float m = acc;
    #pragma unroll
    for (int o = 32; o > 0; o >>= 1) m = fmaxf(m, __shfl_xor(m, o));
    float p = __expf(acc - m);
    float s = p;
    #pragma unroll
    for (int o = 32; o > 0; o >>= 1) s += __shfl_xor(s, o);
    float prob = p / s;

    float myp = prob;
    float kw[TOPK]; int kid[TOPK]; float wsum = 0.f;
    #pragma unroll
    for (int k = 0; k < TOPK; ++k) {
        float v = myp; int bi = e;
        #pragma unroll
        for (int o = 32; o > 0; o >>= 1) {
            float ov = __shfl_xor(v, o);
            int   oi = __shfl_xor(bi, o);
            if (ov > v || (ov == v && oi < bi)) { v = ov; bi = oi; }
        }
        kw[k] = v; kid[k] = bi; wsum += v;
        if (e == bi) myp = -1.f;
    }
    if (e == 0) {
        float inv = 1.f / wsum;
        #pragma unroll
        for (int k = 0; k < TOPK; ++k) {
            topk_idx[t * TOPK + k] = kid[k];
            topk_w[t * TOPK + k]   = kw[k] * inv;
        }
    }
}

__global__ __launch_bounds__(64) void listbuild_kernel(
    const int* __restrict__ topk_idx, const float* __restrict__ topk_w,
    int* __restrict__ counts, int* __restrict__ lists, float* __restrict__ wlist)
{
    const int e = blockIdx.x;
    const int lane = threadIdx.x;
    int n = 0;
    for (int base = 0; base < NTOK * TOPK; base += 64) {
        int s = base + lane;
        int idx = topk_idx[s];
        bool match = (idx == e);
        unsigned long long mask = __ballot(match);
        int pre = __popcll(mask & ((1ull << lane) - 1ull));
        if (match) {
            lists[e * NTOK + n + pre] = s >> 3;
            wlist[e * NTOK + n + pre] = topk_w[s];
        }
        n += __popcll(mask);
    }
    if (lane == 0) counts[e] = n;
}

__global__ __launch_bounds__(64) void scan_kernel(
    const int* __restrict__ counts, int* __restrict__ offsets)
{
    int e = threadIdx.x;
    int v = counts[e];
    int xacc = v;
    #pragma unroll
    for (int o = 1; o < 64; o <<= 1) {
        int y = __shfl_up(xacc, o);
        if (e >= o) xacc += y;
    }
    offsets[e] = xacc - v;
}

#define MFMA_BF16 __builtin_amdgcn_mfma_f32_16x16x32_bf16

// ---------------- gate+up: grid 1536 (xcd-swizzled), block 512 ----------------
// 8 waves = 4 M-pos (48 rows) x 2 N-pos (16 cols); BM=192, BN=32.
// A (x rows bf16) staged in LDS [192][40]; B (weights fp32->bf16) [2buf][2mat][32n][20w]
__global__ __launch_bounds__(512) void gateup_kernel(
    const unsigned short* __restrict__ xbf,
    const float* __restrict__ Wg, const float* __restrict__ Wu,
    const int* __restrict__ counts, const int* __restrict__ offsets,
    const int* __restrict__ lists, const float* __restrict__ wlist,
    unsigned short* __restrict__ hmid)
{
    const int b  = blockIdx.x;
    const int wg = (b & 7) * 192 + (b >> 3);     // bijective: 1536 = 8*192
    const int itile = wg % 24;                   // 24 itiles of 32 cols
    const int e     = wg / 24;

    const int count = counts[e];
    if (count == 0) return;
    const int off = offsets[e];
    const int i0 = itile * 32;

    __shared__ unsigned short Alds[BMT][40];     // 15360 B (2-way max on b128 r/w)
    __shared__ u32 Blds[2][2][32 * 20];          // 10240 B (2-way max with n*20+4q b128)

    const int tid  = threadIdx.x;
    const int lane = tid & 63;
    const int wid  = tid >> 6;
    const int wm   = wid >> 1, wn = wid & 1;
    const int kb   = lane >> 4;
    const int l15  = lane & 15;

    // B staging: tid 0-255 -> (mat, col n, k-octet q)
    const bool bstage = tid < 256;
    const int  bmat   = (tid >> 7) & 1;
    const int  bn     = tid & 31;
    const int  bq     = (tid >> 5) & 3;
    const float* WB = (bmat ? Wu : Wg) + (size_t)e * H_DIM * I_DIM + i0 + bn;
    // A staging: tid 128-511 -> (row, 16-short half)
    const bool astage = tid >= 128;
    const int  ar = (tid - 128) >> 1;
    const int  ah = (tid & 1) * 16;

    for (int mstart = 0; mstart < count; mstart += BMT) {
        const int pr = mstart + ar;
        const bool aact = astage && (pr < count);
        const unsigned short* xrow = xbf + (size_t)(aact ? lists[e * NTOK + (pr < count ? pr : 0)] : 0) * H_DIM + ah;
        const bool mact = (mstart + wm * 48) < count;

        f32x4 accg[3], accu[3];
        #pragma unroll
        for (int i = 0; i < 3; ++i) {
            accg[i] = (f32x4){0.f, 0.f, 0.f, 0.f};
            accu[i] = (f32x4){0.f, 0.f, 0.f, 0.f};
        }

        u32x4 pA0, pA1;
        float a0, a1, a2, a3, a4, a5, a6, a7;   // B prefetch set A
        float c0, c1, c2, c3, c4, c5, c6, c7;   // B prefetch set B

#define GU_LOADB(S0,S1,S2,S3,S4,S5,S6,S7,h)                                     \
        if (bstage) {                                                           \
            const float* p_ = WB + (size_t)((h) + 8 * bq) * I_DIM;              \
            S0 = NTLOAD(p_);             S1 = NTLOAD(p_ + I_DIM);               \
            S2 = NTLOAD(p_ + 2 * I_DIM); S3 = NTLOAD(p_ + 3 * I_DIM);           \
            S4 = NTLOAD(p_ + 4 * I_DIM); S5 = NTLOAD(p_ + 5 * I_DIM);           \
            S6 = NTLOAD(p_ + 6 * I_DIM); S7 = NTLOAD(p_ + 7 * I_DIM);           \
        }
#define GU_STOREB(S0,S1,S2,S3,S4,S5,S6,S7,bufi)                                 \
        if (bstage) {                                                           \
            u32x4 w_;                                                           \
            w_.x = pack2(S0, S1); w_.y = pack2(S2, S3);                         \
            w_.z = pack2(S4, S5); w_.w = pack2(S6, S7);                         \
            *(u32x4*)&Blds[bufi][bmat][bn * 20 + 4 * bq] = w_;                  \
        }
#define GU_LOADA(h)                                                             \
        if (aact) {                                                             \
            const u32x4* pa_ = (const u32x4*)(xrow + (h));                      \
            pA0 = pa_[0]; pA1 = pa_[1];                                         \
        }
#define GU_STOREA()                                                             \
        if (aact) {                                                             \
            *(u32x4*)&Alds[ar][ah]     = pA0;                                   \
            *(u32x4*)&Alds[ar][ah + 8] = pA1;                                   \
        }
#define GU_MFMA(bufi)                                                           \
        if (mact) {                                                             \
            bf16v8 af0 = *(const bf16v8*)&Alds[wm * 48 + l15][kb * 8];          \
            bf16v8 af1 = *(const bf16v8*)&Alds[wm * 48 + 16 + l15][kb * 8];     \
            bf16v8 af2 = *(const bf16v8*)&Alds[wm * 48 + 32 + l15][kb * 8];     \
            bf16v8 bg = *(const bf16v8*)&Blds[bufi][0][(wn * 16 + l15) * 20 + kb * 4]; \
            bf16v8 bu = *(const bf16v8*)&Blds[bufi][1][(wn * 16 + l15) * 20 + kb * 4]; \
            accg[0] = MFMA_BF16(af0, bg, accg[0], 0, 0, 0);                     \
            accu[0] = MFMA_BF16(af0, bu, accu[0], 0, 0, 0);                     \
            accg[1] = MFMA_BF16(af1, bg, accg[1], 0, 0, 0);                     \
            accu[1] = MFMA_BF16(af1, bu, accu[1], 0, 0, 0);                     \
            accg[2] = MFMA_BF16(af2, bg, accg[2], 0, 0, 0);                     \
            accu[2] = MFMA_BF16(af2, bu, accu[2], 0, 0, 0);                     \
        }

        GU_LOADB(a0,a1,a2,a3,a4,a5,a6,a7, 0);
        GU_LOADB(c0,c1,c2,c3,c4,c5,c6,c7, BKS);
        GU_LOADA(0);

        for (int t = 0; t < 64; t += 2) {
            GU_STOREA(); GU_STOREB(a0,a1,a2,a3,a4,a5,a6,a7, 0);
            __syncthreads();
            if (t + 2 < 64) GU_LOADB(a0,a1,a2,a3,a4,a5,a6,a7, (t + 2) * BKS);
            GU_LOADA((t + 1) * BKS);
            GU_MFMA(0);
            __syncthreads();

            GU_STOREA(); GU_STOREB(c0,c1,c2,c3,c4,c5,c6,c7, 1);
            __syncthreads();
            if (t + 3 < 64) GU_LOADB(c0,c1,c2,c3,c4,c5,c6,c7, (t + 3) * BKS);
            if (t + 2 < 64) GU_LOADA((t + 2) * BKS);
            GU_MFMA(1);
            __syncthreads();
        }
#undef GU_LOADB
#undef GU_STOREB
#undef GU_LOADA
#undef GU_STOREA
#undef GU_MFMA

        // epilogue: silu(g)*u*w -> hmid (bf16)
        if (mact) {
            #pragma unroll
            for (int mf = 0; mf < 3; ++mf)
                #pragma unroll
                for (int r = 0; r < 4; ++r) {
                    int pos = mstart + wm * 48 + mf * 16 + kb * 4 + r;
                    if (pos < count) {
                        float wgt = wlist[e * NTOK + pos];
                        float g = accg[mf][r], u = accu[mf][r];
                        float s = 1.f / (1.f + __expf(-g));
                        hmid[(size_t)(off + pos) * I_DIM + i0 + wn * 16 + l15] = f2bf(g * s * u * wgt);
                    }
                }
        }
    }
}

// ---------------- down: grid 4096 (xcd-swizzled), block 512 ----------------
__global__ __launch_bounds__(512) void down_kernel(
    const unsigned short* __restrict__ hmid, const float* __restrict__ Wd,
    const int* __restrict__ counts, const int* __restrict__ offsets,
    const int* __restrict__ lists, float* __restrict__ out)
{
    const int b  = blockIdx.x;
    const int wg = (b & 7) * 512 + (b >> 3);     // bijective: 4096 = 8*512
    const int htile = wg % 64;                   // 64 htiles of 32 cols
    const int e     = wg / 64;

    const int count = counts[e];
    if (count == 0) return;
    const int off = offsets[e];
    const int h0 = htile * 32;

    __shared__ unsigned short Alds[BMT][40];     // 15360 B
    __shared__ u32 Blds[2][32 * 20];             // 5120 B

    const int tid  = threadIdx.x;
    const int lane = tid & 63;
    const int wid  = tid >> 6;
    const int wm   = wid >> 1, wn = wid & 1;
    const int kb   = lane >> 4;
    const int l15  = lane & 15;

    const bool bstage = tid < 128;
    const int  bn     = tid & 31;
    const int  bq     = (tid >> 5) & 3;
    const float* WB = Wd + (size_t)e * I_DIM * H_DIM + h0 + bn;
    const bool astage = tid >= 128;
    const int  ar = (tid - 128) >> 1;
    const int  ah = (tid & 1) * 16;

    for (int mstart = 0; mstart < count; mstart += BMT) {
        const int pr = mstart + ar;
        const bool aact = astage && (pr < count);
        const unsigned short* hrow = hmid + (size_t)(off + (aact ? pr : 0)) * I_DIM + ah;
        const bool mact = (mstart + wm * 48) < count;

        f32x4 acc[3];
        #pragma unroll
        for (int i = 0; i < 3; ++i) acc[i] = (f32x4){0.f, 0.f, 0.f, 0.f};

        u32x4 pA0, pA1;
        float a0, a1, a2, a3, a4, a5, a6, a7;
        float c0, c1, c2, c3, c4, c5, c6, c7;

#define DN_LOADB(S0,S1,S2,S3,S4,S5,S6,S7,h)                                     \
        if (bstage) {                                                           \
            const float* p_ = WB + (size_t)((h) + 8 * bq) * H_DIM;              \
            S0 = NTLOAD(p_);             S1 = NTLOAD(p_ + H_DIM);               \
            S2 = NTLOAD(p_ + 2 * H_DIM); S3 = NTLOAD(p_ + 3 * H_DIM);           \
            S4 = NTLOAD(p_ + 4 * H_DIM); S5 = NTLOAD(p_ + 5 * H_DIM);           \
            S6 = NTLOAD(p_ + 6 * H_DIM); S7 = NTLOAD(p_ + 7 * H_DIM);           \
        }
#define DN_STOREB(S0,S1,S2,S3,S4,S5,S6,S7,bufi)                                 \
        if (bstage) {                                                           \
            u32x4 w_;                                                           \
            w_.x = pack2(S0, S1); w_.y = pack2(S2, S3);                         \
            w_.z = pack2(S4, S5); w_.w = pack2(S6, S7);                         \
            *(u32x4*)&Blds[bufi][bn * 20 + 4 * bq] = w_;                        \
        }
#define DN_LOADA(h)                                                             \
        if (aact) {                                                             \
            const u32x4* pa_ = (const u32x4*)(hrow + (h));                      \
            pA0 = pa_[0]; pA1 = pa_[1];                                         \
        }
#define DN_STOREA()                                                             \
        if (aact) {                                                             \
            *(u32x4*)&Alds[ar][ah]     = pA0;                                   \
            *(u32x4*)&Alds[ar][ah + 8] = pA1;                                   \
        }
#define DN_MFMA(bufi)                                                           \
        if (mact) {                                                             \
            bf16v8 af0 = *(const bf16v8*)&Alds[wm * 48 + l15][kb * 8];          \
            bf16v8 af1 = *(const bf16v8*)&Alds[wm * 48 + 16 + l15][kb * 8];     \
            bf16v8 af2 = *(const bf16v8*)&Alds[wm * 48 + 32 + l15][kb * 8];     \
            bf16v8 bd = *(const bf16v8*)&Blds[bufi][(wn * 16 + l15) * 20 + kb * 4]; \
            acc[0] = MFMA_BF16(af0, bd, acc[0], 0, 0, 0);                       \
            acc[1] = MFMA_BF16(af1, bd, acc[1], 0, 0, 0);                       \
            acc[2] = MFMA_BF16(af2, bd, acc[2], 0, 0, 0);                       \
        }

        DN_LOADB(a0,a1,a2,a3,a4,a5,a6,a7, 0);
        DN_LOADB(c0,c1,c2,c3,c4,c5,c6,c7, BKS);
        DN_LOADA(0);

        for (int t = 0; t < 24; t += 2) {
            DN_STOREA(); DN_STOREB(a0,a1,a2,a3,a4,a5,a6,a7, 0);
            __syncthreads();
            if (t + 2 < 24) DN_LOADB(a0,a1,a2,a3,a4,a5,a6,a7, (t + 2) * BKS);
            DN_LOADA((t + 1) * BKS);
            DN_MFMA(0);
            __syncthreads();

            DN_STOREA(); DN_STOREB(c0,c1,c2,c3,c4,c5,c6,c7, 1);
            __syncthreads();
            if (t + 3 < 24) DN_LOADB(c0,c1,c2,c3,c4,c5,c6,c7, (t + 3) * BKS);
            if (t + 2 < 24) DN_LOADA((t + 2) * BKS);
            DN_MFMA(1);
            __syncthreads();
        }
#undef DN_LOADB
#undef DN_STOREB
#undef DN_LOADA
#undef DN_STOREA
#undef DN_MFMA

        if (mact) {
            #pragma unroll
            for (int mf = 0; mf < 3; ++mf)
                #pragma unroll
                for (int r = 0; r < 4; ++r) {
                    int pos = mstart + wm * 48 + mf * 16 + kb * 4 + r;
                    if (pos < count) {
                        int tok = lists[e * NTOK + pos];
                        atomicAdd(&out[(size_t)tok * H_DIM + h0 + wn * 16 + l15],
                                  acc[mf][r]);
                    }
                }
        }
    }
}

extern "C" void kernel_launch(void* const* d_in, const int* in_sizes, int n_in,
                              void* d_out, int out_size, void* d_ws, size_t ws_size,
                              hipStream_t stream) {
    const float* x  = (const float*)d_in[0];
    const float* Wr = (const float*)d_in[1];
    const float* Wg = (const float*)d_in[2];
    const float* Wu = (const float*)d_in[3];
    const float* Wd = (const float*)d_in[4];
    float* out = (float*)d_out;

    char* ws = (char*)d_ws;
    int*   topk_idx = (int*)  (ws + 0);
    float* topk_w   = (float*)(ws + 32768);
    int*   counts   = (int*)  (ws + 65536);
    int*   offsets  = (int*)  (ws + 65792);
    int*   lists    = (int*)  (ws + 66048);
    float* wlist    = (float*)(ws + 328192);
    unsigned short* hmid = (unsigned short*)(ws + 590336);
    unsigned short* xbf  = (unsigned short*)(ws + 13173248);

    const int nout4 = NTOK * H_DIM / 4;
    hipLaunchKernelGGL(zero_kernel, dim3((nout4 + 255) / 256), dim3(256), 0, stream,
                       (float4*)out, nout4);
    hipLaunchKernelGGL(xconv_kernel, dim3((NTOK * H_DIM / 4 + 255) / 256), dim3(256), 0, stream,
                       (const float4*)x, (ushort4*)xbf, NTOK * H_DIM / 4);
    hipLaunchKernelGGL(router_kernel, dim3(NTOK), dim3(64), 0, stream,
                       x, Wr, topk_idx, topk_w);
    hipLaunchKernelGGL(listbuild_kernel, dim3(NEXP), dim3(64), 0, stream,
                       topk_idx, topk_w, counts, lists, wlist);
    hipLaunchKernelGGL(scan_kernel, dim3(1), dim3(64), 0, stream,
                       counts, offsets);
    hipLaunchKernelGGL(gateup_kernel, dim3(24 * NEXP), dim3(512), 0, stream,
                       xbf, Wg, Wu, counts, offsets, lists, wlist, hmid);
    hipLaunchKernelGGL(down_kernel, dim3(64 * NEXP), dim3(512), 0, stream,
                       hmid, Wd, counts, offsets, lists, out);
}

// Round 9
// 489.243 us; speedup vs baseline: 1.3384x; 1.2710x over previous
//
#include <hip/hip_runtime.h>
#include <hip/hip_bf16.h>

#define H_DIM 2048
#define I_DIM 768
#define NEXP 64
#define TOPK 8
#define NTOK 1024   // B*S
#define BM 256      // token tile (count ~128+-11 => single chunk)
#define BKS 32      // K per step

typedef float f32x4 __attribute__((ext_vector_type(4)));
typedef unsigned int u32x4 __attribute__((ext_vector_type(4)));
typedef unsigned int u32x2 __attribute__((ext_vector_type(2)));
typedef short bf16v8 __attribute__((ext_vector_type(8)));   // 8 bf16 in 4 VGPRs
typedef unsigned short u16x8 __attribute__((ext_vector_type(8)));
typedef unsigned int u32;

#define NTLOAD __builtin_nontemporal_load

// ---------------- workspace layout (bytes) ----------------
// topk_idx : int   [NTOK*TOPK]           @ 0
// topk_w   : float [NTOK*TOPK]           @ 32768
// counts   : int   [NEXP]                @ 65536
// offsets  : int   [NEXP]                @ 65792
// lists    : int   [NEXP*NTOK]           @ 66048    (ends 328192)
// wlist    : float [NEXP*NTOK]           @ 328192   (ends 590336)
// inv      : int   [NTOK*TOPK]           @ 590336   (ends 623104)
// hmid     : bf16  [NTOK*TOPK * I_DIM]   @ 623104   (ends 13206016)
// xbf      : bf16  [NTOK * H_DIM]        @ 13206016 (ends 17400320)
// part     : bf16  [NTOK*TOPK * H_DIM]   @ 17400320 (ends 50954752)
#define WS_NEEDED 50954752ull

__device__ inline unsigned short f2bf(float f) {
    union { float f; u32 u; } v; v.f = f;
    u32 r = (v.u + 0x7FFFu + ((v.u >> 16) & 1u)) >> 16;
    return (unsigned short)r;
}
__device__ inline u32 pack2(float a, float b) {
    return (u32)f2bf(a) | ((u32)f2bf(b) << 16);
}

__global__ void zero_kernel(float4* p, int n4) {
    int i = blockIdx.x * blockDim.x + threadIdx.x;
    if (i < n4) p[i] = (float4){0.f, 0.f, 0.f, 0.f};
}

__global__ void xconv_kernel(const float4* __restrict__ x, ushort4* __restrict__ xbf, int n4) {
    int i = blockIdx.x * blockDim.x + threadIdx.x;
    if (i < n4) {
        float4 v = x[i];
        ushort4 o;
        o.x = f2bf(v.x); o.y = f2bf(v.y); o.z = f2bf(v.z); o.w = f2bf(v.w);
        xbf[i] = o;
    }
}

// one block per token, 256 threads: 4 waves split K (512 iters each), then
// wave 0 does softmax + iterative top-8 (identical selection logic to R1-R8).
__global__ __launch_bounds__(256) void router_kernel(
    const float* __restrict__ x, const float* __restrict__ Wr,
    int* __restrict__ topk_idx, float* __restrict__ topk_w)
{
    const int t   = blockIdx.x;
    const int tid = threadIdx.x;
    const int lane = tid & 63;
    const int wv   = tid >> 6;           // 0..3 -> K chunk
    __shared__ float xs[H_DIM];
    __shared__ float red[4][64];

    const float* xrow = x + (size_t)t * H_DIM;
    {
        const float4* src = (const float4*)xrow;
        float4* dst = (float4*)xs;
        dst[tid]       = src[tid];
        dst[tid + 256] = src[tid + 256];
    }
    __syncthreads();

    float acc = 0.f;
    const int h0 = wv * 512;
    #pragma unroll 8
    for (int h = h0; h < h0 + 512; ++h) acc += xs[h] * Wr[(size_t)h * NEXP + lane];
    red[wv][lane] = acc;
    __syncthreads();

    if (tid < 64) {
        const int e = tid;
        float logit = red[0][e] + red[1][e] + red[2][e] + red[3][e];

        float m = logit;
        #pragma unroll
        for (int o = 32; o > 0; o >>= 1) m = fmaxf(m, __shfl_xor(m, o));
        float p = __expf(logit - m);
        float s = p;
        #pragma unroll
        for (int o = 32; o > 0; o >>= 1) s += __shfl_xor(s, o);
        float prob = p / s;

        float myp = prob;
        float kw[TOPK]; int kid[TOPK]; float wsum = 0.f;
        #pragma unroll
        for (int k = 0; k < TOPK; ++k) {
            float v = myp; int bi = e;
            #pragma unroll
            for (int o = 32; o > 0; o >>= 1) {
                float ov = __shfl_xor(v, o);
                int   oi = __shfl_xor(bi, o);
                if (ov > v || (ov == v && oi < bi)) { v = ov; bi = oi; }
            }
            kw[k] = v; kid[k] = bi; wsum += v;
            if (e == bi) myp = -1.f;
        }
        if (e == 0) {
            float inv = 1.f / wsum;
            #pragma unroll
            for (int k = 0; k < TOPK; ++k) {
                topk_idx[t * TOPK + k] = kid[k];
                topk_w[t * TOPK + k]   = kw[k] * inv;
            }
        }
    }
}

// one wave per expert; deterministic ordered compaction + inverse rank map
__global__ __launch_bounds__(64) void listbuild_kernel(
    const int* __restrict__ topk_idx, const float* __restrict__ topk_w,
    int* __restrict__ counts, int* __restrict__ lists, float* __restrict__ wlist,
    int* __restrict__ invmap)
{
    const int e = blockIdx.x;
    const int lane = threadIdx.x;
    int n = 0;
    for (int base = 0; base < NTOK * TOPK; base += 64) {
        int s = base + lane;
        int idx = topk_idx[s];
        bool match = (idx == e);
        unsigned long long mask = __ballot(match);
        int pre = __popcll(mask & ((1ull << lane) - 1ull));
        if (match) {
            lists[e * NTOK + n + pre] = s >> 3;
            wlist[e * NTOK + n + pre] = topk_w[s];
            invmap[s] = n + pre;               // rank within expert e's list
        }
        n += __popcll(mask);
    }
    if (lane == 0) counts[e] = n;
}

__global__ __launch_bounds__(64) void scan_kernel(
    const int* __restrict__ counts, int* __restrict__ offsets)
{
    int e = threadIdx.x;
    int v = counts[e];
    int xacc = v;
    #pragma unroll
    for (int o = 1; o < 64; o <<= 1) {
        int y = __shfl_up(xacc, o);
        if (e >= o) xacc += y;
    }
    offsets[e] = xacc - v;
}

#define MFMA_BF16 __builtin_amdgcn_mfma_f32_16x16x32_bf16

// ---------------- MFMA gate+up: grid 1536 (xcd-swizzled), block 512, BN=32 ----------------
// (exact R6 structure -- best measured 246 us)
__global__ __launch_bounds__(512) void gateup_kernel(
    const unsigned short* __restrict__ xbf,
    const float* __restrict__ Wg, const float* __restrict__ Wu,
    const int* __restrict__ counts, const int* __restrict__ offsets,
    const int* __restrict__ lists, const float* __restrict__ wlist,
    unsigned short* __restrict__ hmid)
{
    const int b  = blockIdx.x;
    const int wg = (b & 7) * 192 + (b >> 3);
    const int itile = wg % 24;
    const int e     = wg / 24;

    const int count = counts[e];
    if (count == 0) return;
    const int off = offsets[e];
    const int i0 = itile * 32;

    __shared__ unsigned short Alds[BM][40];
    __shared__ u32 Bgl[32 * 20];
    __shared__ u32 Bul[32 * 20];

    const int tid  = threadIdx.x;
    const int lane = tid & 63;
    const int wid  = tid >> 6;
    const int wm   = wid >> 1, wn = wid & 1;
    const int kb   = lane >> 4;
    const int l15  = lane & 15;

    const float* WgE = Wg + (size_t)e * H_DIM * I_DIM + i0;
    const float* WuE = Wu + (size_t)e * H_DIM * I_DIM + i0;

    const int ar = tid >> 1;
    const int ah = (tid & 1) * 16;
    const int bnn  = tid & 31;
    const int bkq  = (tid >> 5) & 7;
    const int bmat = tid >> 8;
    const float* WB = (bmat ? Wu : Wg) + (size_t)e * H_DIM * I_DIM + i0 + bnn;
    const int key4w = 4 * ((bnn >> 3) & 3);
    u32* bdst = (bmat ? Bul : Bgl) + bnn * 20 + ((2 * bkq) ^ key4w);
    const int brn   = wn * 16 + l15;
    const int key4r = 4 * ((brn >> 3) & 3);

    for (int mstart = 0; mstart < count; mstart += BM) {
        const int pr = mstart + ar;
        const bool aact = pr < count;
        const unsigned short* xrow = xbf + (size_t)(aact ? lists[e * NTOK + pr] : 0) * H_DIM + ah;
        const bool mact = (mstart + wm * 64) < count;

        f32x4 accg[4], accu[4];
        #pragma unroll
        for (int i = 0; i < 4; ++i) {
            accg[i] = (f32x4){0.f, 0.f, 0.f, 0.f};
            accu[i] = (f32x4){0.f, 0.f, 0.f, 0.f};
        }

        u32x4 pA0, pA1;
        float b0a, b1a, b2a, b3a;
        float b0b, b1b, b2b, b3b;

#define GU_LOADA(h)                                                             \
        if (aact) {                                                             \
            const u32x4* pa_ = (const u32x4*)(xrow + (h));                      \
            pA0 = pa_[0]; pA1 = pa_[1];                                         \
        }
#define GU_LOADB(R0,R1,R2,R3,h)                                                 \
        {                                                                       \
            R0 = NTLOAD(WB + (size_t)((h) + 4 * bkq)     * I_DIM);              \
            R1 = NTLOAD(WB + (size_t)((h) + 4 * bkq + 1) * I_DIM);              \
            R2 = NTLOAD(WB + (size_t)((h) + 4 * bkq + 2) * I_DIM);              \
            R3 = NTLOAD(WB + (size_t)((h) + 4 * bkq + 3) * I_DIM);              \
        }
#define GU_STOREA()                                                             \
        if (aact) {                                                             \
            *(u32x4*)&Alds[ar][ah]     = pA0;                                   \
            *(u32x4*)&Alds[ar][ah + 8] = pA1;                                   \
        }
#define GU_STOREB(R0,R1,R2,R3)                                                  \
        {                                                                       \
            u32x2 w_; w_.x = pack2(R0, R1); w_.y = pack2(R2, R3);               \
            *(u32x2*)bdst = w_;                                                 \
        }
#define GU_MFMA()                                                               \
        if (mact) {                                                             \
            bf16v8 af[4], bg, bu;                                               \
            _Pragma("unroll")                                                   \
            for (int mf = 0; mf < 4; ++mf)                                      \
                af[mf] = *(const bf16v8*)&Alds[wm * 64 + mf * 16 + l15][kb * 8];\
            bg = *(const bf16v8*)&Bgl[brn * 20 + ((4 * kb) ^ key4r)];           \
            bu = *(const bf16v8*)&Bul[brn * 20 + ((4 * kb) ^ key4r)];           \
            _Pragma("unroll")                                                   \
            for (int mf = 0; mf < 4; ++mf) {                                    \
                accg[mf] = MFMA_BF16(af[mf], bg, accg[mf], 0, 0, 0);            \
                accu[mf] = MFMA_BF16(af[mf], bu, accu[mf], 0, 0, 0);            \
            }                                                                   \
        }

        GU_LOADB(b0a, b1a, b2a, b3a, 0);
        GU_LOADB(b0b, b1b, b2b, b3b, BKS);
        GU_LOADA(0);

        for (int hh = 0; hh < H_DIM; hh += 2 * BKS) {
            GU_STOREA(); GU_STOREB(b0a, b1a, b2a, b3a);
            __syncthreads();
            if (hh + 2 * BKS < H_DIM) GU_LOADB(b0a, b1a, b2a, b3a, hh + 2 * BKS);
            GU_LOADA(hh + BKS);
            GU_MFMA();
            __syncthreads();

            GU_STOREA(); GU_STOREB(b0b, b1b, b2b, b3b);
            __syncthreads();
            if (hh + 3 * BKS < H_DIM) GU_LOADB(b0b, b1b, b2b, b3b, hh + 3 * BKS);
            if (hh + 2 * BKS < H_DIM) GU_LOADA(hh + 2 * BKS);
            GU_MFMA();
            __syncthreads();
        }
#undef GU_LOADA
#undef GU_LOADB
#undef GU_STOREA
#undef GU_STOREB
#undef GU_MFMA

        if (mact) {
            #pragma unroll
            for (int mf = 0; mf < 4; ++mf)
                #pragma unroll
                for (int r = 0; r < 4; ++r) {
                    int pos = mstart + wm * 64 + mf * 16 + kb * 4 + r;
                    if (pos < count) {
                        float wgt = wlist[e * NTOK + pos];
                        float g = accg[mf][r], u = accu[mf][r];
                        float s = 1.f / (1.f + __expf(-g));
                        hmid[(size_t)(off + pos) * I_DIM + i0 + wn * 16 + l15] = f2bf(g * s * u * wgt);
                    }
                }
        }
    }
}

// ---------------- MFMA down: grid 4096 (xcd-swizzled), block 512, BN=32 ----------------
// (exact R6 core; epilogue: bf16 partial store (USE_PART) or atomicAdd fallback)
template <bool USE_PART>
__global__ __launch_bounds__(512) void down_kernel(
    const unsigned short* __restrict__ hmid, const float* __restrict__ Wd,
    const int* __restrict__ counts, const int* __restrict__ offsets,
    const int* __restrict__ lists, float* __restrict__ out,
    unsigned short* __restrict__ part)
{
    const int b  = blockIdx.x;
    const int wg = (b & 7) * 512 + (b >> 3);
    const int htile = wg % 64;
    const int e     = wg / 64;

    const int count = counts[e];
    if (count == 0) return;
    const int off = offsets[e];
    const int h0 = htile * 32;

    __shared__ unsigned short Alds[BM][40];
    __shared__ u32 Bdl[32 * 20];

    const int tid  = threadIdx.x;
    const int lane = tid & 63;
    const int wid  = tid >> 6;
    const int wm   = wid >> 1, wn = wid & 1;
    const int kb   = lane >> 4;
    const int l15  = lane & 15;

    const int ar = tid >> 1;
    const int ah = (tid & 1) * 16;
    const int bnn  = tid & 31;
    const int bkq  = (tid >> 5) & 7;
    const bool bact = tid < 256;
    const float* WB = Wd + (size_t)e * I_DIM * H_DIM + h0 + bnn;
    const int key4w = 4 * ((bnn >> 3) & 3);
    u32* bdst = Bdl + bnn * 20 + ((2 * bkq) ^ key4w);
    const int brn   = wn * 16 + l15;
    const int key4r = 4 * ((brn >> 3) & 3);

    for (int mstart = 0; mstart < count; mstart += BM) {
        const int pr = mstart + ar;
        const bool aact = pr < count;
        const unsigned short* hrow = hmid + (size_t)(off + (aact ? pr : 0)) * I_DIM + ah;
        const bool mact = (mstart + wm * 64) < count;

        f32x4 acc[4];
        #pragma unroll
        for (int i = 0; i < 4; ++i) acc[i] = (f32x4){0.f, 0.f, 0.f, 0.f};

        u32x4 pH0, pH1;
        float d0a, d1a, d2a, d3a;
        float d0b, d1b, d2b, d3b;

#define DN_LOADA(k)                                                             \
        if (aact) {                                                             \
            const u32x4* p_ = (const u32x4*)(hrow + (k));                       \
            pH0 = p_[0]; pH1 = p_[1];                                           \
        }
#define DN_LOADB(R0,R1,R2,R3,k)                                                 \
        if (bact) {                                                             \
            R0 = NTLOAD(WB + (size_t)((k) + 4 * bkq)     * H_DIM);              \
            R1 = NTLOAD(WB + (size_t)((k) + 4 * bkq + 1) * H_DIM);              \
            R2 = NTLOAD(WB + (size_t)((k) + 4 * bkq + 2) * H_DIM);              \
            R3 = NTLOAD(WB + (size_t)((k) + 4 * bkq + 3) * H_DIM);              \
        }
#define DN_STOREA()                                                             \
        if (aact) {                                                             \
            *(u32x4*)&Alds[ar][ah]     = pH0;                                   \
            *(u32x4*)&Alds[ar][ah + 8] = pH1;                                   \
        }
#define DN_STOREB(R0,R1,R2,R3)                                                  \
        if (bact) {                                                             \
            u32x2 w_; w_.x = pack2(R0, R1); w_.y = pack2(R2, R3);               \
            *(u32x2*)bdst = w_;                                                 \
        }
#define DN_MFMA()                                                               \
        if (mact) {                                                             \
            bf16v8 af[4], bd;                                                   \
            _Pragma("unroll")                                                   \
            for (int mf = 0; mf < 4; ++mf)                                      \
                af[mf] = *(const bf16v8*)&Alds[wm * 64 + mf * 16 + l15][kb * 8];\
            bd = *(const bf16v8*)&Bdl[brn * 20 + ((4 * kb) ^ key4r)];           \
            _Pragma("unroll")                                                   \
            for (int mf = 0; mf < 4; ++mf)                                      \
                acc[mf] = MFMA_BF16(af[mf], bd, acc[mf], 0, 0, 0);              \
        }

        DN_LOADB(d0a, d1a, d2a, d3a, 0);
        DN_LOADB(d0b, d1b, d2b, d3b, BKS);
        DN_LOADA(0);

        for (int ii = 0; ii < I_DIM; ii += 2 * BKS) {
            DN_STOREA(); DN_STOREB(d0a, d1a, d2a, d3a);
            __syncthreads();
            if (ii + 2 * BKS < I_DIM) DN_LOADB(d0a, d1a, d2a, d3a, ii + 2 * BKS);
            DN_LOADA(ii + BKS);
            DN_MFMA();
            __syncthreads();

            DN_STOREA(); DN_STOREB(d0b, d1b, d2b, d3b);
            __syncthreads();
            if (ii + 3 * BKS < I_DIM) DN_LOADB(d0b, d1b, d2b, d3b, ii + 3 * BKS);
            if (ii + 2 * BKS < I_DIM) DN_LOADA(ii + 2 * BKS);
            DN_MFMA();
            __syncthreads();
        }
#undef DN_LOADA
#undef DN_LOADB
#undef DN_STOREA
#undef DN_STOREB
#undef DN_MFMA

        if (mact) {
            #pragma unroll
            for (int mf = 0; mf < 4; ++mf)
                #pragma unroll
                for (int r = 0; r < 4; ++r) {
                    int pos = mstart + wm * 64 + mf * 16 + kb * 4 + r;
                    if (pos < count) {
                        if constexpr (USE_PART) {
                            part[(size_t)(off + pos) * H_DIM + h0 + wn * 16 + l15] =
                                f2bf(acc[mf][r]);
                        } else {
                            int tok = lists[e * NTOK + pos];
                            atomicAdd(&out[(size_t)tok * H_DIM + h0 + wn * 16 + l15],
                                      acc[mf][r]);
                        }
                    }
                }
        }
    }
}

// one block per token: sum its 8 partial rows (bf16) in fp32 -> out
__global__ __launch_bounds__(256) void reduce_kernel(
    const unsigned short* __restrict__ part,
    const int* __restrict__ topk_idx, const int* __restrict__ invmap,
    const int* __restrict__ offsets, float* __restrict__ out)
{
    const int t   = blockIdx.x;
    const int tid = threadIdx.x;
    __shared__ int slots[TOPK];
    if (tid < TOPK) {
        int s = t * TOPK + tid;
        slots[tid] = offsets[topk_idx[s]] + invmap[s];
    }
    __syncthreads();

    const int c = tid * 8;
    float acc[8] = {0.f, 0.f, 0.f, 0.f, 0.f, 0.f, 0.f, 0.f};
    #pragma unroll
    for (int k = 0; k < TOPK; ++k) {
        u16x8 v = *(const u16x8*)&part[(size_t)slots[k] * H_DIM + c];
        #pragma unroll
        for (int j = 0; j < 8; ++j)
            acc[j] += __uint_as_float((u32)(unsigned short)v[j] << 16);
    }
    float4* dst = (float4*)&out[(size_t)t * H_DIM + c];
    dst[0] = (float4){acc[0], acc[1], acc[2], acc[3]};
    dst[1] = (float4){acc[4], acc[5], acc[6], acc[7]};
}

extern "C" void kernel_launch(void* const* d_in, const int* in_sizes, int n_in,
                              void* d_out, int out_size, void* d_ws, size_t ws_size,
                              hipStream_t stream) {
    const float* x  = (const float*)d_in[0];
    const float* Wr = (const float*)d_in[1];
    const float* Wg = (const float*)d_in[2];
    const float* Wu = (const float*)d_in[3];
    const float* Wd = (const float*)d_in[4];
    float* out = (float*)d_out;

    char* ws = (char*)d_ws;
    int*   topk_idx = (int*)  (ws + 0);
    float* topk_w   = (float*)(ws + 32768);
    int*   counts   = (int*)  (ws + 65536);
    int*   offsets  = (int*)  (ws + 65792);
    int*   lists    = (int*)  (ws + 66048);
    float* wlist    = (float*)(ws + 328192);
    int*   invmap   = (int*)  (ws + 590336);
    unsigned short* hmid = (unsigned short*)(ws + 623104);
    unsigned short* xbf  = (unsigned short*)(ws + 13206016);
    unsigned short* part = (unsigned short*)(ws + 17400320);

    const bool usePart = ws_size >= WS_NEEDED;

    hipLaunchKernelGGL(xconv_kernel, dim3((NTOK * H_DIM / 4 + 255) / 256), dim3(256), 0, stream,
                       (const float4*)x, (ushort4*)xbf, NTOK * H_DIM / 4);
    hipLaunchKernelGGL(router_kernel, dim3(NTOK), dim3(256), 0, stream,
                       x, Wr, topk_idx, topk_w);
    hipLaunchKernelGGL(listbuild_kernel, dim3(NEXP), dim3(64), 0, stream,
                       topk_idx, topk_w, counts, lists, wlist, invmap);
    hipLaunchKernelGGL(scan_kernel, dim3(1), dim3(64), 0, stream,
                       counts, offsets);
    hipLaunchKernelGGL(gateup_kernel, dim3(24 * NEXP), dim3(512), 0, stream,
                       xbf, Wg, Wu, counts, offsets, lists, wlist, hmid);
    if (usePart) {
        hipLaunchKernelGGL((down_kernel<true>), dim3(64 * NEXP), dim3(512), 0, stream,
                           hmid, Wd, counts, offsets, lists, out, part);
        hipLaunchKernelGGL(reduce_kernel, dim3(NTOK), dim3(256), 0, stream,
                           part, topk_idx, invmap, offsets, out);
    } else {
        const int nout4 = NTOK * H_DIM / 4;
        hipLaunchKernelGGL(zero_kernel, dim3((nout4 + 255) / 256), dim3(256), 0, stream,
                           (float4*)out, nout4);
        hipLaunchKernelGGL((down_kernel<false>), dim3(64 * NEXP), dim3(512), 0, stream,
                           hmid, Wd, counts, offsets, lists, out, part);
    }
}